// Round 8
// baseline (130.795 us; speedup 1.0000x reference)
//
#include <hip/hip_runtime.h>
#include <hip/hip_bf16.h>

typedef __attribute__((ext_vector_type(8))) short short8;
typedef __attribute__((ext_vector_type(4))) float f32x4;
typedef unsigned short u16;
typedef unsigned int u32;

// B=512, M=40, H=128, D=64, C=128.
// Factored algebra: out[c,d] = sum_m x0[m,d] * T_m[c,d],
//   T_m[c,d] = sum_h W[c,h,m] * xk[h,d]   (pure bf16 GEMM, K=H=128)
// Telescoped (Abel): T accumulates over m; out += dd_m * T_m with
// dd_m = x0[m] - x0[m+1] (x0[40]=0), precomputed in LDS as F32
// (R7 lesson: bf16 dd -> absmax 0.219 > 0.17; f32 dd is exactly the
// R0-R3 proven arithmetic, absmax 0.03125).
//
// Perf ledger R0-R6: all structures pinned at MfmaUtil 30-38%. Per-SIMD
// budget (19.4 cyc per 16x16x32 MFMA): R3's waves stall ~450 cyc/body on
// depth-2 A-prefetch -- L2 QUEUING latency at 13-15 TB/s aggregate
// A-stream (~56% of per-XCD L2 BW). R8: halve A-traffic (2 batches share
// each A-load; 671->336 MB) while keeping R3's barrier-free reg-ring
// loop. K-split keeps bR at 64 regs; 4-wave blocks avoid residency
// granularity loss; f32 dd fits via 3-phase LDS overlay (xkT dead after
// B-frag caching -> dd written over it).
#define NB 512
#define NM 40
#define NH 128
#define ND 64
#define NC 128
#define KTOT 5120

__device__ __forceinline__ u16 f2bf_rne(float f) {
    u32 u = __float_as_uint(f);
    u32 r = u + 0x7FFFu + ((u >> 16) & 1u);
    return (u16)(r >> 16);
}

// W fp32 [C][h*40+m] -> bf16 W3 granule layout: 16B granule (m,t,q,c) at
// byte ((m*16 + t*4 + q)*128 + c)*16, holding W[c][h=t*32+q*8+j][m], j=0..7.
// (Proven rounds 0-7.)
__global__ void w3_kernel(const float* __restrict__ W, u16* __restrict__ W3) {
    __shared__ u16 kbuf[NH * 20];          // [h][mo], m-half only
    const int c = blockIdx.x >> 1, mh = blockIdx.x & 1;
    const float* src = W + (size_t)c * KTOT + mh * 20;
    for (int i = threadIdx.x; i < NH * 5; i += 256) {   // i = h*5 + j4
        int h = i / 5, j4 = i % 5;
        float4 v = *(const float4*)(src + h * NM + j4 * 4);
        u16* kb = kbuf + h * 20 + j4 * 4;
        kb[0] = f2bf_rne(v.x); kb[1] = f2bf_rne(v.y);
        kb[2] = f2bf_rne(v.z); kb[3] = f2bf_rne(v.w);
    }
    __syncthreads();
    for (int i = threadIdx.x; i < 320; i += 256) {      // i = mo*16 + t*4 + q
        int mo = i >> 4, t = (i >> 2) & 3, q = i & 3;
        int n = (mh * 20 + mo) * 16 + t * 4 + q;
        union { short8 s8; u16 e[8]; } v;
#pragma unroll
        for (int j = 0; j < 8; ++j)
            v.e[j] = kbuf[(t * 32 + q * 8 + j) * 20 + mo];
        *(short8*)(W3 + ((size_t)n * 128 + c) * 8) = v.s8;
    }
}

// main: grid 1024 = pair(256 of 2 batches) x c-quarter(4, fast index),
// 256 thr = 4 waves = rh(2 c-slices of 16) x kh(2 k-halves of 64).
// Wave: 16c x 64d x 64k x 2 BATCHES -- each A-granule (1KB) feeds 8 MFMAs
// and is read by half as many blocks as R3 -> L2 A-traffic 671->336 MB.
// Body u = m*2+th (80): 1 A-load (depth-2 reg ring), 8 MFMA, telescope
// (f32 dd from LDS) at th==1. NO in-loop barriers or LDS writes.
// 3-phase prologue: xkT -> sync -> B-frags to regs -> sync -> f32 dd
// overlays xkT -> sync. LDS 35.3KB -> 3 blocks/CU at (256,3).
// Epilogue: kh-pair LDS reduce (R6/R7-proven mechanism), overlays dd.
__global__ void __launch_bounds__(256, 3) cin_main(
    const float* __restrict__ x0g, const float* __restrict__ xkg,
    const float* __restrict__ biasg, const u16* __restrict__ W3,
    float* __restrict__ out)
{
    // region0 [0,34816): xkT bf16 [2][64][136] (phase 1-2)
    //   -> x0d f32 [2][40][68] = 21760 (phase 3 + main loop)
    //   -> red f32 [2 rh][2 b2][64 d][20 c-pad] = 20480 (epilogue)
    // bias f32 @34816 ; total 35328 B -> 3 blocks/CU (106 KB).
    __shared__ __align__(16) char smem[35328];
    short* xkT    = (short*)smem;
    float* x0d    = (float*)smem;
    float* bias_s = (float*)(smem + 34816);

    const int tid = threadIdx.x;
    const int w = tid >> 6, L = tid & 63;
    const int q = L >> 4, l16 = L & 15;
    const int kh = w & 1;                   // k-half: h in [kh*64, +64)
    const int rh = w >> 1;                  // c-slice within quarter
    const int cq = blockIdx.x & 3;          // c-quarter (fast: spreads L2)
    const size_t b0 = 2 * (size_t)(blockIdx.x >> 2);

    // A-granule source, body u (m=u>>1, th=u&1), lane (q,l16):
    //   byte = m*32768 + (kh*2+th)*8192 + q*2048 + (cq*32+rh*16+l16)*16
    const char* A0 = (const char*)W3
        + (size_t)(kh * 16384 + q * 2048 + (cq * 32 + rh * 16 + l16) * 16);

    short8 aP[2];                           // depth-2 register ring
    aP[0] = *(const short8*)(A0);
    aP[1] = *(const short8*)(A0 + 8192);

    // ---- phase 1: 2 batches xk -> bf16 xkT (transposed, stride 136); bias
    for (int i = tid; i < 4096; i += 256) {           // (b2, h, d4)
        int b2 = i >> 11, rem = i & 2047;
        int h = rem >> 4, d4 = (rem & 15) << 2;
        float4 v = *(const float4*)(xkg + (b0 + b2) * (NH * ND) + h * ND + d4);
        short* xT = xkT + b2 * 8704;
        xT[(d4 + 0) * 136 + h] = (short)f2bf_rne(v.x);
        xT[(d4 + 1) * 136 + h] = (short)f2bf_rne(v.y);
        xT[(d4 + 2) * 136 + h] = (short)f2bf_rne(v.z);
        xT[(d4 + 3) * 136 + h] = (short)f2bf_rne(v.w);
    }
    if (tid < NC) bias_s[tid] = biasg[tid];
    __syncthreads();

    // ---- phase 2: B frag register cache (half-K, 2 batches):
    // bR[b2][th][n] = xk[b2][h=kh*64+th*32+q*8+j][d=n*16+l16]
    short8 bR[2][2][4];
#pragma unroll
    for (int b2 = 0; b2 < 2; ++b2) {
        const short* Bp = xkT + b2 * 8704 + (size_t)l16 * 136 + kh * 64 + q * 8;
#pragma unroll
        for (int th = 0; th < 2; ++th)
#pragma unroll
            for (int n = 0; n < 4; ++n)
                bR[b2][th][n] = *(const short8*)(Bp + n * (16 * 136) + th * 32);
    }
    __syncthreads();                         // xkT dead -> overlay with dd

    // ---- phase 3: dd = x0[m]-x0[m+1] (f32) -> x0d over region0
    for (int i = tid; i < 1280; i += 256) {           // (b2, m, d4)
        int b2 = i / 640, rem = i % 640;
        int m = rem >> 4, d4 = (rem & 15) << 2;
        const float* xp = x0g + (b0 + b2) * (NM * ND) + m * ND + d4;
        float4 cur = *(const float4*)xp;
        float4 nxt = make_float4(0.f, 0.f, 0.f, 0.f);
        if (m < 39) nxt = *(const float4*)(xp + ND);
        f32x4 dv;
        dv[0] = cur.x - nxt.x; dv[1] = cur.y - nxt.y;
        dv[2] = cur.z - nxt.z; dv[3] = cur.w - nxt.w;
        *(f32x4*)(x0d + b2 * 2720 + m * 68 + d4) = dv;
    }
    __syncthreads();

    const float* dd0 = x0d + (size_t)l16;    // + b2*2720 + m*68 + n*16

    f32x4 T[2][4] = {};      // cumulative GEMM acc per batch
    f32x4 o[2][4] = {};      // scaled output acc per batch

#pragma unroll 4
    for (int u = 0; u < 80; ++u) {           // u = m*2 + th
        const int th = u & 1;
        const short8 a = aP[u & 1];
        // prefetch body u+2 into the just-consumed slot (clamped tail)
        const int up = (u + 2 < 80) ? (u + 2) : 79;
        aP[u & 1] = *(const short8*)(A0 + (size_t)(up >> 1) * 32768
                                        + (size_t)(up & 1) * 8192);
        T[0][0] = __builtin_amdgcn_mfma_f32_16x16x32_bf16(a, bR[0][th][0], T[0][0], 0, 0, 0);
        T[0][1] = __builtin_amdgcn_mfma_f32_16x16x32_bf16(a, bR[0][th][1], T[0][1], 0, 0, 0);
        T[0][2] = __builtin_amdgcn_mfma_f32_16x16x32_bf16(a, bR[0][th][2], T[0][2], 0, 0, 0);
        T[0][3] = __builtin_amdgcn_mfma_f32_16x16x32_bf16(a, bR[0][th][3], T[0][3], 0, 0, 0);
        T[1][0] = __builtin_amdgcn_mfma_f32_16x16x32_bf16(a, bR[1][th][0], T[1][0], 0, 0, 0);
        T[1][1] = __builtin_amdgcn_mfma_f32_16x16x32_bf16(a, bR[1][th][1], T[1][1], 0, 0, 0);
        T[1][2] = __builtin_amdgcn_mfma_f32_16x16x32_bf16(a, bR[1][th][2], T[1][2], 0, 0, 0);
        T[1][3] = __builtin_amdgcn_mfma_f32_16x16x32_bf16(a, bR[1][th][3], T[1][3], 0, 0, 0);
        if (th == 1) {       // telescoped scale: out += dd_m * T_m (f32 dd)
            const int m = u >> 1;
#pragma unroll
            for (int b2 = 0; b2 < 2; ++b2)
#pragma unroll
                for (int n = 0; n < 4; ++n) {
                    const float dd = dd0[b2 * 2720 + m * 68 + n * 16];
                    o[b2][n] += dd * T[b2][n];
                }
        }
    }

    // ---- epilogue: kh-pair reduce in LDS (overlay region0)
    __syncthreads();
    float* red = (float*)smem;               // [2 rh][2 b2][64 d][20]
    float* myred = red + (rh * 2) * 1280;
    if (kh == 1) {
#pragma unroll
        for (int b2 = 0; b2 < 2; ++b2)
#pragma unroll
            for (int n = 0; n < 4; ++n) {
                int d = n * 16 + l16;
                *(f32x4*)(myred + b2 * 1280 + d * 20 + q * 4) = o[b2][n];
            }
    }
    __syncthreads();
    if (kh == 0) {
#pragma unroll
        for (int b2 = 0; b2 < 2; ++b2) {
            float* op = out + (b0 + b2) * (NC * ND);
#pragma unroll
            for (int n = 0; n < 4; ++n) {
                int d = n * 16 + l16;
                f32x4 r = *(const f32x4*)(myred + b2 * 1280 + d * 20 + q * 4);
#pragma unroll
                for (int rr = 0; rr < 4; ++rr) {
                    int c = cq * 32 + rh * 16 + q * 4 + rr;
                    op[c * ND + d] = o[b2][n][rr] + r[rr] + bias_s[c];
                }
            }
        }
    }
}

extern "C" void kernel_launch(void* const* d_in, const int* in_sizes, int n_in,
                              void* d_out, int out_size, void* d_ws, size_t ws_size,
                              hipStream_t stream) {
    const float* x0 = (const float*)d_in[0];
    const float* xk = (const float*)d_in[1];
    const float* W  = (const float*)d_in[2];
    const float* bi = (const float*)d_in[3];
    float* out = (float*)d_out;

    u16* W3 = (u16*)d_ws;                      // 655360 shorts = 1.31 MB

    w3_kernel<<<NC * 2, 256, 0, stream>>>(W, W3);
    cin_main<<<NB / 2 * 4, 256, 0, stream>>>(x0, xk, bi, W3, out);
}

// Round 9
// 130.268 us; speedup vs baseline: 1.0041x; 1.0041x over previous
//
#include <hip/hip_runtime.h>
#include <hip/hip_bf16.h>

typedef __attribute__((ext_vector_type(8))) short short8;
typedef __attribute__((ext_vector_type(4))) float f32x4;
typedef unsigned short u16;
typedef unsigned int u32;

// B=512, M=40, H=128, D=64, C=128.
// Factored algebra: out[c,d] = sum_m x0[m,d] * T_m[c,d],
//   T_m[c,d] = sum_h W[c,h,m] * xk[h,d]   (pure bf16 GEMM, K=H=128)
// Telescoped (Abel): T accumulates over m; out += dd_m * T_m,
// dd_m = x0[m] - x0[m+1] (x0[40]=0), f32 in LDS (R8-proven numerics).
//
// R0-R8 ledger: every barrier-free structure converges to ~14-15 TB/s
// total L2-side traffic (R0/R1 13.8, R3 14.7, R4 13.2) with MfmaUtil
// pinned 33-38% -- a bandwidth-ceiling signature for this broadcast
// A-stream (the 34.5 TB/s L2 ubench includes L1 reuse; true stream
// ceiling here ~15 TB/s). R5/R7/R8 cut A-bytes but paid in barriers or
// occupancy. R9: cut A-bytes 4x via L1 SHARING -- 4 waves (4 batches)
// per block read IDENTICAL granule addresses, so 3 of 4 reads are L1
// hits. No LDS staging, no in-loop sync except a raw s_barrier drift
// limiter every 8 m. A L2-traffic 671 -> 168 MB.
#define NB 512
#define NM 40
#define NH 128
#define ND 64
#define NC 128
#define KTOT 5120

__device__ __forceinline__ u16 f2bf_rne(float f) {
    u32 u = __float_as_uint(f);
    u32 r = u + 0x7FFFu + ((u >> 16) & 1u);
    return (u16)(r >> 16);
}

// W fp32 [C][h*40+m] -> bf16 W3 granule layout: 16B granule (m,t,q,c) at
// byte ((m*16 + t*4 + q)*128 + c)*16, holding W[c][h=t*32+q*8+j][m], j=0..7.
// (Proven rounds 0-8.)
__global__ void w3_kernel(const float* __restrict__ W, u16* __restrict__ W3) {
    __shared__ u16 kbuf[NH * 20];          // [h][mo], m-half only
    const int c = blockIdx.x >> 1, mh = blockIdx.x & 1;
    const float* src = W + (size_t)c * KTOT + mh * 20;
    for (int i = threadIdx.x; i < NH * 5; i += 256) {   // i = h*5 + j4
        int h = i / 5, j4 = i % 5;
        float4 v = *(const float4*)(src + h * NM + j4 * 4);
        u16* kb = kbuf + h * 20 + j4 * 4;
        kb[0] = f2bf_rne(v.x); kb[1] = f2bf_rne(v.y);
        kb[2] = f2bf_rne(v.z); kb[3] = f2bf_rne(v.w);
    }
    __syncthreads();
    for (int i = threadIdx.x; i < 320; i += 256) {      // i = mo*16 + t*4 + q
        int mo = i >> 4, t = (i >> 2) & 3, q = i & 3;
        int n = (mh * 20 + mo) * 16 + t * 4 + q;
        union { short8 s8; u16 e[8]; } v;
#pragma unroll
        for (int j = 0; j < 8; ++j)
            v.e[j] = kbuf[(t * 32 + q * 8 + j) * 20 + mo];
        *(short8*)(W3 + ((size_t)n * 128 + c) * 8) = v.s8;
    }
}

// main: grid 512 = group(128 of 4 batches) x c-quarter(4, fast index),
// 256 thr = 4 waves = 4 BATCHES (wave v owns batch b0+v). ALL waves cover
// the SAME c-range [cq*32, cq*32+32) -> identical A addresses -> L1 hits.
// Wave tile: 32c x 64d x 128k. Body u = (m,t), 160 bodies: 2 A-loads
// (two 16c granule halves, depth-2 reg ring), 8 MFMA, dd-telescope at
// t==3. bR from direct global gather (no LDS; keeps 3 blocks/CU).
// ~156 regs -> 3 waves/SIMD; 4-wave blocks -> 3 blocks/CU = 12 waves.
__global__ void __launch_bounds__(256, 3) cin_main(
    const float* __restrict__ x0g, const float* __restrict__ xkg,
    const float* __restrict__ biasg, const u16* __restrict__ W3,
    float* __restrict__ out)
{
    // x0d f32 [4][40][68] = 43520 | bias 512 @43520 ; 44032 B -> 3 blk/CU
    __shared__ __align__(16) char smem[44032];
    float* x0d    = (float*)smem;
    float* bias_s = (float*)(smem + 43520);

    const int tid = threadIdx.x;
    const int v = tid >> 6, L = tid & 63;   // v = wave = batch index
    const int q = L >> 4, l16 = L & 15;
    const int cq = blockIdx.x & 3;          // c-quarter (fast index)
    const size_t b0 = 4 * (size_t)(blockIdx.x >> 2);

    // A address, body u=(m,t), lane (q,l16), half s:
    //   byte = m*32768 + t*8192 + q*2048 + cq*512 + s*256 + l16*16
    // NOTE: independent of v -> all 4 waves load identical addresses.
    const char* A0 = (const char*)W3 + q * 2048 + cq * 512 + l16 * 16;

    short8 aP[2][2];                        // depth-2 ring x 2 halves
    aP[0][0] = *(const short8*)(A0);
    aP[0][1] = *(const short8*)(A0 + 256);
    aP[1][0] = *(const short8*)(A0 + 8192);
    aP[1][1] = *(const short8*)(A0 + 8192 + 256);

    // ---- bR via direct global gather (one-time; no LDS):
    // bR[t][n].e[j] = bf16(xk[b0+v][h=t*32+q*8+j][d=n*16+l16])
    const float* xkb = xkg + (b0 + v) * (NH * ND);
    short8 bR[4][4];
#pragma unroll
    for (int t = 0; t < 4; ++t)
#pragma unroll
        for (int n = 0; n < 4; ++n) {
            union { short8 s8; u16 e[8]; } tmp;
#pragma unroll
            for (int j = 0; j < 8; ++j)
                tmp.e[j] = f2bf_rne(xkb[(t * 32 + q * 8 + j) * ND + n * 16 + l16]);
            bR[t][n] = tmp.s8;
        }

    // ---- dd = x0[m]-x0[m+1] (f32) -> LDS
    for (int i = tid; i < 2560; i += 256) {           // (b2, m, d4)
        int b2 = i / 640, rem = i % 640;
        int m = rem >> 4, d4 = (rem & 15) << 2;
        const float* xp = x0g + (b0 + b2) * (NM * ND) + m * ND + d4;
        float4 cur = *(const float4*)xp;
        float4 nxt = make_float4(0.f, 0.f, 0.f, 0.f);
        if (m < 39) nxt = *(const float4*)(xp + ND);
        f32x4 dv;
        dv[0] = cur.x - nxt.x; dv[1] = cur.y - nxt.y;
        dv[2] = cur.z - nxt.z; dv[3] = cur.w - nxt.w;
        *(f32x4*)(x0d + b2 * 2720 + m * 68 + d4) = dv;
    }
    if (tid < NC) bias_s[tid] = biasg[tid];
    __syncthreads();

    const float* dd0 = x0d + v * 2720 + (size_t)l16;  // + m*68 + n*16

    f32x4 T[2][4] = {};      // cumulative GEMM acc (2 x 16c rows)
    f32x4 o[2][4] = {};      // scaled output acc

#pragma unroll 4
    for (int u = 0; u < 160; ++u) {          // u = m*4 + t
        const int t = u & 3;
        const short8 a0 = aP[u & 1][0];
        const short8 a1 = aP[u & 1][1];
        // prefetch body u+2 into the just-consumed slot (clamped tail)
        const int up = (u + 2 < 160) ? (u + 2) : 159;
        const char* p = A0 + (size_t)(up >> 2) * 32768 + (size_t)(up & 3) * 8192;
        aP[u & 1][0] = *(const short8*)p;
        aP[u & 1][1] = *(const short8*)(p + 256);
        T[0][0] = __builtin_amdgcn_mfma_f32_16x16x32_bf16(a0, bR[t][0], T[0][0], 0, 0, 0);
        T[0][1] = __builtin_amdgcn_mfma_f32_16x16x32_bf16(a0, bR[t][1], T[0][1], 0, 0, 0);
        T[0][2] = __builtin_amdgcn_mfma_f32_16x16x32_bf16(a0, bR[t][2], T[0][2], 0, 0, 0);
        T[0][3] = __builtin_amdgcn_mfma_f32_16x16x32_bf16(a0, bR[t][3], T[0][3], 0, 0, 0);
        T[1][0] = __builtin_amdgcn_mfma_f32_16x16x32_bf16(a1, bR[t][0], T[1][0], 0, 0, 0);
        T[1][1] = __builtin_amdgcn_mfma_f32_16x16x32_bf16(a1, bR[t][1], T[1][1], 0, 0, 0);
        T[1][2] = __builtin_amdgcn_mfma_f32_16x16x32_bf16(a1, bR[t][2], T[1][2], 0, 0, 0);
        T[1][3] = __builtin_amdgcn_mfma_f32_16x16x32_bf16(a1, bR[t][3], T[1][3], 0, 0, 0);
        if (t == 3) {        // telescoped scale: out += dd_m * T_m (f32 dd)
            const int m = u >> 2;
#pragma unroll
            for (int n = 0; n < 4; ++n) {
                const float dd = dd0[m * 68 + n * 16];
                o[0][n] += dd * T[0][n];
                o[1][n] += dd * T[1][n];
            }
        }
        // drift limiter: keep the 4 sharing waves within the L1 window.
        // raw barrier (no vmcnt drain) -- pure rendezvous, no data exchange.
        if ((u & 31) == 31) __builtin_amdgcn_s_barrier();
    }

    // ---- epilogue: direct store (wave owns 32c x 64d of its batch)
    float* op = out + (b0 + v) * (NC * ND);
#pragma unroll
    for (int mt = 0; mt < 2; ++mt)
#pragma unroll
        for (int n = 0; n < 4; ++n) {
            const int d = n * 16 + l16;
#pragma unroll
            for (int rr = 0; rr < 4; ++rr) {
                const int c = cq * 32 + mt * 16 + q * 4 + rr;
                op[c * ND + d] = o[mt][n][rr] + bias_s[c];
            }
        }
}

extern "C" void kernel_launch(void* const* d_in, const int* in_sizes, int n_in,
                              void* d_out, int out_size, void* d_ws, size_t ws_size,
                              hipStream_t stream) {
    const float* x0 = (const float*)d_in[0];
    const float* xk = (const float*)d_in[1];
    const float* W  = (const float*)d_in[2];
    const float* bi = (const float*)d_in[3];
    float* out = (float*)d_out;

    u16* W3 = (u16*)d_ws;                      // 655360 shorts = 1.31 MB

    w3_kernel<<<NC * 2, 256, 0, stream>>>(W, W3);
    cin_main<<<NB / 4 * 4, 256, 0, stream>>>(x0, xk, bi, W3, out);
}